// Round 1
// baseline (60.434 us; speedup 1.0000x reference)
//
#include <hip/hip_runtime.h>
#include <math.h>

#define B 8
#define N 2048
#define D 3072
#define NCHUNK 16
#define CHUNK (N / NCHUNK)   // 128

// ---- device helpers ----------------------------------------------------

struct Scalars {
    float state_scale;  // sqrt(1 + var_tilde)
    float inv_2vt;      // 1 / (2 * var_tilde)
    float alpha;
    float inv_sigma;
};

__device__ inline Scalars compute_scalars(const float* __restrict__ ng) {
    float gamma = ng[0] * 25.0f - 15.0f;            // *(GAMMA_MAX-GAMMA_MIN)+GAMMA_MIN
    float var_tilde = expf(-gamma);
    float variance = 1.0f / (1.0f + expf(gamma));   // sigmoid(-gamma)
    Scalars s;
    s.state_scale = sqrtf(1.0f + var_tilde);
    s.inv_2vt     = 0.5f / var_tilde;
    s.alpha       = sqrtf(1.0f - variance);
    s.inv_sigma   = 1.0f / sqrtf(variance);
    return s;
}

// ---- K1: sse[b][n] = sum_d ((in[b,d]*ss - train[n,d]) * mask[d])^2 -----
// one block per n; 256 threads stride over D; f64 accumulation.

__global__ __launch_bounds__(256) void k_sse(
        const float* __restrict__ in, const float* __restrict__ ng,
        const float* __restrict__ mask, const float* __restrict__ train,
        float* __restrict__ sse_out) {
    const int n   = blockIdx.x;
    const int tid = threadIdx.x;
    const Scalars sc = compute_scalars(ng);

    double acc[B];
#pragma unroll
    for (int b = 0; b < B; ++b) acc[b] = 0.0;

    const float* trow = train + (size_t)n * D;
    for (int d = tid; d < D; d += 256) {
        float t = trow[d];
        float m = mask[d];
#pragma unroll
        for (int b = 0; b < B; ++b) {
            float s = in[b * D + d] * sc.state_scale;
            float diff = (s - t) * m;
            acc[b] += (double)diff * (double)diff;
        }
    }

    // wave (64-lane) butterfly, then cross-wave via LDS
#pragma unroll
    for (int b = 0; b < B; ++b)
        for (int off = 32; off; off >>= 1)
            acc[b] += __shfl_down(acc[b], off);

    __shared__ double red[4][B];
    const int wave = tid >> 6, lane = tid & 63;
    if (lane == 0) {
#pragma unroll
        for (int b = 0; b < B; ++b) red[wave][b] = acc[b];
    }
    __syncthreads();
    if (tid < B) {
        double s = red[0][tid] + red[1][tid] + red[2][tid] + red[3][tid];
        sse_out[tid * N + n] = (float)s;
    }
}

// ---- K2: softmax over n per b; writes probT[n*8 + b] --------------------

__global__ __launch_bounds__(256) void k_softmax(
        const float* __restrict__ sse, const float* __restrict__ ng,
        float* __restrict__ probT) {
    const int b   = blockIdx.x;
    const int tid = threadIdx.x;
    const Scalars sc = compute_scalars(ng);
    const float* row = sse + b * N;

    // pass 1: max of log-likelihood
    float mx = -INFINITY;
    for (int n = tid; n < N; n += 256)
        mx = fmaxf(mx, -row[n] * sc.inv_2vt);
    for (int off = 32; off; off >>= 1)
        mx = fmaxf(mx, __shfl_xor(mx, off));
    __shared__ float smx[4];
    if ((tid & 63) == 0) smx[tid >> 6] = mx;
    __syncthreads();
    mx = fmaxf(fmaxf(smx[0], smx[1]), fmaxf(smx[2], smx[3]));

    // pass 2: sum of exp
    float sum = 0.0f;
    for (int n = tid; n < N; n += 256)
        sum += expf(-row[n] * sc.inv_2vt - mx);
    for (int off = 32; off; off >>= 1)
        sum += __shfl_xor(sum, off);
    __shared__ float ssum[4];
    if ((tid & 63) == 0) ssum[tid >> 6] = sum;
    __syncthreads();
    const float inv = 1.0f / (ssum[0] + ssum[1] + ssum[2] + ssum[3]);

    // pass 3: write normalized probs, transposed for K3
    for (int n = tid; n < N; n += 256)
        probT[n * B + b] = expf(-row[n] * sc.inv_2vt - mx) * inv;
}

// ---- K3: partial denoised sums over n-chunks ----------------------------
// grid (3, NCHUNK); thread owns 4 consecutive d (float4).
// partials[(c*B + b)*D + d] = sum_{n in chunk c} probT[n][b] * train[n][d]

__device__ inline void fma4(float4& a, float p, const float4& t) {
    a.x = fmaf(p, t.x, a.x);
    a.y = fmaf(p, t.y, a.y);
    a.z = fmaf(p, t.z, a.z);
    a.w = fmaf(p, t.w, a.w);
}

__global__ __launch_bounds__(256) void k_denoise_partial(
        const float* __restrict__ train, const float* __restrict__ probT,
        float* __restrict__ partials) {
    const int d4 = blockIdx.x * 256 + threadIdx.x;   // 0..767
    const int c  = blockIdx.y;                       // 0..NCHUNK-1
    const int d  = d4 * 4;

    float4 acc[B];
#pragma unroll
    for (int b = 0; b < B; ++b) acc[b] = make_float4(0.f, 0.f, 0.f, 0.f);

    const int n0 = c * CHUNK;
    for (int n = n0; n < n0 + CHUNK; ++n) {
        const float4 t  = *(const float4*)(train + (size_t)n * D + d);
        const float4 p0 = *(const float4*)(probT + n * B);
        const float4 p1 = *(const float4*)(probT + n * B + 4);
        fma4(acc[0], p0.x, t); fma4(acc[1], p0.y, t);
        fma4(acc[2], p0.z, t); fma4(acc[3], p0.w, t);
        fma4(acc[4], p1.x, t); fma4(acc[5], p1.y, t);
        fma4(acc[6], p1.z, t); fma4(acc[7], p1.w, t);
    }
#pragma unroll
    for (int b = 0; b < B; ++b)
        *(float4*)(partials + ((size_t)(c * B + b)) * D + d) = acc[b];
}

// ---- K4: reduce partials + epilogue -------------------------------------

__global__ __launch_bounds__(256) void k_eps(
        const float* __restrict__ in, const float* __restrict__ ng,
        const float* __restrict__ mask, const float* __restrict__ partials,
        float* __restrict__ out) {
    const int i = blockIdx.x * 256 + threadIdx.x;    // < B*D
    const int b = i / D;
    const int d = i - b * D;
    const Scalars sc = compute_scalars(ng);

    float s = 0.0f;
#pragma unroll
    for (int c = 0; c < NCHUNK; ++c)
        s += partials[((size_t)(c * B + b)) * D + d];

    out[i] = (in[i] - sc.alpha * s) * sc.inv_sigma * mask[d];
}

// ---- launch --------------------------------------------------------------

extern "C" void kernel_launch(void* const* d_in, const int* in_sizes, int n_in,
                              void* d_out, int out_size, void* d_ws, size_t ws_size,
                              hipStream_t stream) {
    const float* in    = (const float*)d_in[0];   // [8,3,32,32]
    const float* ng    = (const float*)d_in[1];   // [1]
    const float* mask  = (const float*)d_in[2];   // [3,32,32]
    const float* train = (const float*)d_in[3];   // [2048,3,32,32]
    float* out = (float*)d_out;

    float* ws       = (float*)d_ws;
    float* sse      = ws;                  // B*N   = 16384 floats
    float* probT    = ws + B * N;          // N*B   = 16384 floats
    float* partials = ws + 2 * B * N;      // NCHUNK*B*D = 393216 floats

    k_sse<<<N, 256, 0, stream>>>(in, ng, mask, train, sse);
    k_softmax<<<B, 256, 0, stream>>>(sse, ng, probT);
    k_denoise_partial<<<dim3(D / 4 / 256, NCHUNK), 256, 0, stream>>>(train, probT, partials);
    k_eps<<<(B * D) / 256, 256, 0, stream>>>(in, ng, mask, partials, out);
}

// Round 2
// 34.642 us; speedup vs baseline: 1.7445x; 1.7445x over previous
//
#include <hip/hip_runtime.h>
#include <math.h>

#define B 8
#define N 2048
#define D 3072
#define NCHUNK 64
#define CHUNK (N / NCHUNK)   // 32

// ---- device helpers ----------------------------------------------------

struct Scalars {
    float state_scale;  // sqrt(1 + var_tilde)
    float inv_2vt;      // 1 / (2 * var_tilde)
    float alpha;
    float inv_sigma;
};

__device__ inline Scalars compute_scalars(const float* __restrict__ ng) {
    float gamma = ng[0] * 25.0f - 15.0f;            // *(GAMMA_MAX-GAMMA_MIN)+GAMMA_MIN
    float var_tilde = expf(-gamma);
    float variance = 1.0f / (1.0f + expf(gamma));   // sigmoid(-gamma)
    Scalars s;
    s.state_scale = sqrtf(1.0f + var_tilde);
    s.inv_2vt     = 0.5f / var_tilde;
    s.alpha       = sqrtf(1.0f - variance);
    s.inv_sigma   = 1.0f / sqrtf(variance);
    return s;
}

// ---- K1: sse[b][n] = sum_d ((in[b,d]*ss - train[n,d]) * mask[d])^2 -----
// one block per n; 256 threads, float4 over D (3 iters); f64 accumulation
// (keeps argmax robust when softmax temperature is razor-sharp).

__global__ __launch_bounds__(256) void k_sse(
        const float* __restrict__ in, const float* __restrict__ ng,
        const float* __restrict__ mask, const float* __restrict__ train,
        float* __restrict__ sse_out) {
    const int n   = blockIdx.x;
    const int tid = threadIdx.x;
    const Scalars sc = compute_scalars(ng);

    double acc[B];
#pragma unroll
    for (int b = 0; b < B; ++b) acc[b] = 0.0;

    const float* trow = train + (size_t)n * D;
#pragma unroll
    for (int k = 0; k < D / (256 * 4); ++k) {        // 3 iterations
        const int d = (tid + k * 256) * 4;
        const float4 t = *(const float4*)(trow + d);
        const float4 m = *(const float4*)(mask + d);
#pragma unroll
        for (int b = 0; b < B; ++b) {
            const float4 s = *(const float4*)(in + b * D + d);
            float dx = (s.x * sc.state_scale - t.x) * m.x;
            float dy = (s.y * sc.state_scale - t.y) * m.y;
            float dz = (s.z * sc.state_scale - t.z) * m.z;
            float dw = (s.w * sc.state_scale - t.w) * m.w;
            acc[b] += (double)dx * dx + (double)dy * dy
                    + (double)dz * dz + (double)dw * dw;
        }
    }

    // wave (64-lane) butterfly, then cross-wave via LDS
#pragma unroll
    for (int b = 0; b < B; ++b)
        for (int off = 32; off; off >>= 1)
            acc[b] += __shfl_down(acc[b], off);

    __shared__ double red[4][B];
    const int wave = tid >> 6, lane = tid & 63;
    if (lane == 0) {
#pragma unroll
        for (int b = 0; b < B; ++b) red[wave][b] = acc[b];
    }
    __syncthreads();
    if (tid < B) {
        double s = red[0][tid] + red[1][tid] + red[2][tid] + red[3][tid];
        sse_out[tid * N + n] = (float)s;
    }
}

// ---- K2: softmax over n per b; single pass, values in registers ---------
// writes probT[n*8 + b]

__global__ __launch_bounds__(256) void k_softmax(
        const float* __restrict__ sse, const float* __restrict__ ng,
        float* __restrict__ probT) {
    const int b   = blockIdx.x;
    const int tid = threadIdx.x;
    const Scalars sc = compute_scalars(ng);
    const float* row = sse + b * N;

    float v[N / 256];                                // 8 values per thread
#pragma unroll
    for (int k = 0; k < N / 256; ++k)
        v[k] = -row[tid + k * 256] * sc.inv_2vt;

    float mx = v[0];
#pragma unroll
    for (int k = 1; k < N / 256; ++k) mx = fmaxf(mx, v[k]);
    for (int off = 32; off; off >>= 1)
        mx = fmaxf(mx, __shfl_xor(mx, off));
    __shared__ float smx[4];
    if ((tid & 63) == 0) smx[tid >> 6] = mx;
    __syncthreads();
    mx = fmaxf(fmaxf(smx[0], smx[1]), fmaxf(smx[2], smx[3]));

    float e[N / 256];
    float sum = 0.0f;
#pragma unroll
    for (int k = 0; k < N / 256; ++k) {
        e[k] = expf(v[k] - mx);
        sum += e[k];
    }
    for (int off = 32; off; off >>= 1)
        sum += __shfl_xor(sum, off);
    __shared__ float ssum[4];
    if ((tid & 63) == 0) ssum[tid >> 6] = sum;
    __syncthreads();
    const float inv = 1.0f / (ssum[0] + ssum[1] + ssum[2] + ssum[3]);

#pragma unroll
    for (int k = 0; k < N / 256; ++k)
        probT[(tid + k * 256) * B + b] = e[k] * inv;
}

// ---- K3: partial denoised sums over n-chunks ----------------------------
// grid (12, NCHUNK), 64-thread blocks; thread owns 4 consecutive d (float4).
// partials[(c*B + b)*D + d] = sum_{n in chunk c} probT[n][b] * train[n][d]

__device__ inline void fma4(float4& a, float p, const float4& t) {
    a.x = fmaf(p, t.x, a.x);
    a.y = fmaf(p, t.y, a.y);
    a.z = fmaf(p, t.z, a.z);
    a.w = fmaf(p, t.w, a.w);
}

__global__ __launch_bounds__(64) void k_denoise_partial(
        const float* __restrict__ train, const float* __restrict__ probT,
        float* __restrict__ partials) {
    const int d4 = blockIdx.x * 64 + threadIdx.x;    // 0..767
    const int c  = blockIdx.y;                       // 0..NCHUNK-1
    const int d  = d4 * 4;

    float4 acc[B];
#pragma unroll
    for (int b = 0; b < B; ++b) acc[b] = make_float4(0.f, 0.f, 0.f, 0.f);

    const int n0 = c * CHUNK;
#pragma unroll 4
    for (int n = n0; n < n0 + CHUNK; ++n) {
        const float4 t  = *(const float4*)(train + (size_t)n * D + d);
        const float4 p0 = *(const float4*)(probT + n * B);
        const float4 p1 = *(const float4*)(probT + n * B + 4);
        fma4(acc[0], p0.x, t); fma4(acc[1], p0.y, t);
        fma4(acc[2], p0.z, t); fma4(acc[3], p0.w, t);
        fma4(acc[4], p1.x, t); fma4(acc[5], p1.y, t);
        fma4(acc[6], p1.z, t); fma4(acc[7], p1.w, t);
    }
#pragma unroll
    for (int b = 0; b < B; ++b)
        *(float4*)(partials + ((size_t)(c * B + b)) * D + d) = acc[b];
}

// ---- K4: reduce partials + epilogue -------------------------------------
// 384 blocks x 64 threads; each thread one output element.

__global__ __launch_bounds__(64) void k_eps(
        const float* __restrict__ in, const float* __restrict__ ng,
        const float* __restrict__ mask, const float* __restrict__ partials,
        float* __restrict__ out) {
    const int i = blockIdx.x * 64 + threadIdx.x;     // < B*D
    const int b = i / D;
    const int d = i - b * D;
    const Scalars sc = compute_scalars(ng);

    float s = 0.0f;
#pragma unroll 8
    for (int c = 0; c < NCHUNK; ++c)
        s += partials[((size_t)(c * B + b)) * D + d];

    out[i] = (in[i] - sc.alpha * s) * sc.inv_sigma * mask[d];
}

// ---- launch --------------------------------------------------------------

extern "C" void kernel_launch(void* const* d_in, const int* in_sizes, int n_in,
                              void* d_out, int out_size, void* d_ws, size_t ws_size,
                              hipStream_t stream) {
    const float* in    = (const float*)d_in[0];   // [8,3,32,32]
    const float* ng    = (const float*)d_in[1];   // [1]
    const float* mask  = (const float*)d_in[2];   // [3,32,32]
    const float* train = (const float*)d_in[3];   // [2048,3,32,32]
    float* out = (float*)d_out;

    float* ws       = (float*)d_ws;
    float* sse      = ws;                  // B*N   = 16384 floats
    float* probT    = ws + B * N;          // N*B   = 16384 floats
    float* partials = ws + 2 * B * N;      // NCHUNK*B*D = 1.57M floats (6.3 MB)

    k_sse<<<N, 256, 0, stream>>>(in, ng, mask, train, sse);
    k_softmax<<<B, 256, 0, stream>>>(sse, ng, probT);
    k_denoise_partial<<<dim3(D / 4 / 64, NCHUNK), 64, 0, stream>>>(train, probT, partials);
    k_eps<<<(B * D) / 64, 64, 0, stream>>>(in, ng, mask, partials, out);
}